// Round 5
// baseline (92.758 us; speedup 1.0000x reference)
//
#include <hip/hip_runtime.h>
#include <stdint.h>
#include <string.h>

// R5: perf round. Inputs fp32, output fp32 (R4-proven). K1 byte-identical to
// the R4 pass. K2 rewritten: V-fragments register-resident (no per-chunk LDS
// staging), K-dim split across 4 waves, 2 barriers total (was 32), grid
// 1024x256 -> 12-16 waves/CU (was 4). Theory: R4's 92.7us was K2 barrier-
// drain latency exposure at 1 wave/SIMD.

#define NN 512
#define NF 128
#define NC 64

typedef __attribute__((ext_vector_type(8))) short short8;
typedef __attribute__((ext_vector_type(4))) float f32x4;

__device__ __forceinline__ uint16_t f2bf(float f) {
    union { float f; uint32_t u; } v; v.f = f;
    uint32_t u = v.u;
    u += 0x7FFF + ((u >> 16) & 1);   // RNE
    return (uint16_t)(u >> 16);
}

// ---------------------------------------------------------------------------
// K1: feats = X @ kernels[h] via bf16 MFMA (fp32 inputs converted on load).
// Writes: a_s/a_n (fp32 ws), featw = feats^T bf16 [bh][c][n] (ws),
// relu(feats) = emb half of out (FP32). Grid 256 x 256. LDS 34 KB.
// (unchanged from R4 pass)
// ---------------------------------------------------------------------------
__global__ __launch_bounds__(256) void k1_feats(
    const float* __restrict__ X, const float* __restrict__ Kern,
    const float* __restrict__ a_self, const float* __restrict__ a_neigh,
    float* __restrict__ out, uint16_t* __restrict__ featw,
    float* __restrict__ asw, float* __restrict__ anw)
{
    __shared__ __align__(16) uint16_t Kt[64][136];  // kernels[h]^T bf16 [c][f]
    __shared__ float fs[64][65];                    // feats tile fp32 (pad 1)

    const int tid  = threadIdx.x;
    const int lane = tid & 63;
    const int wave = tid >> 6;
    const int blk  = blockIdx.x;
    const int nt   = blk & 7;
    const int bh   = blk >> 3;
    const int h    = bh & 3;
    const int b    = bh >> 2;
    const int nb   = nt * 64;

    // ---- stage Kt[c][f] = bf16(kernels[h][f][c]) ----
    {
        const int f0 = tid >> 1, c0 = (tid & 1) * 32;
        const float* kp = Kern + h * (NF * NC) + f0 * NC + c0;
        #pragma unroll
        for (int s4 = 0; s4 < 8; ++s4) {
            float4 v = *(const float4*)(kp + s4 * 4);
            Kt[c0 + s4 * 4 + 0][f0] = f2bf(v.x);
            Kt[c0 + s4 * 4 + 1][f0] = f2bf(v.y);
            Kt[c0 + s4 * 4 + 2][f0] = f2bf(v.z);
            Kt[c0 + s4 * 4 + 3][f0] = f2bf(v.w);
        }
    }

    // ---- A fragments: X rows, fp32 -> bf16 in registers ----
    const int m = lane & 15;
    const int q = lane >> 4;
    short8 af[4];
    {
        const float* xr = X + ((size_t)(b * NN) + nb + wave * 16 + m) * NF + q * 8;
        #pragma unroll
        for (int kt = 0; kt < 4; ++kt) {
            float4 x0 = *(const float4*)(xr + kt * 32);
            float4 x1 = *(const float4*)(xr + kt * 32 + 4);
            union { uint32_t u[4]; short8 s; } r;
            r.u[0] = (uint32_t)f2bf(x0.x) | ((uint32_t)f2bf(x0.y) << 16);
            r.u[1] = (uint32_t)f2bf(x0.z) | ((uint32_t)f2bf(x0.w) << 16);
            r.u[2] = (uint32_t)f2bf(x1.x) | ((uint32_t)f2bf(x1.y) << 16);
            r.u[3] = (uint32_t)f2bf(x1.z) | ((uint32_t)f2bf(x1.w) << 16);
            af[kt] = r.s;
        }
    }
    __syncthreads();

    // ---- MFMA: wave computes feats[16 rows x 64 c] ----
    #pragma unroll
    for (int ct = 0; ct < 4; ++ct) {
        f32x4 acc = {0.f, 0.f, 0.f, 0.f};
        #pragma unroll
        for (int kt = 0; kt < 4; ++kt) {
            short8 bfr;
            __builtin_memcpy(&bfr, &Kt[ct * 16 + m][kt * 32 + q * 8], 16);
            acc = __builtin_amdgcn_mfma_f32_16x16x32_bf16(af[kt], bfr, acc, 0, 0, 0);
        }
        #pragma unroll
        for (int r = 0; r < 4; ++r)
            fs[wave * 16 + q * 4 + r][ct * 16 + m] = acc[r];   // C: col=m, row=q*4+r
    }

    // ---- a_s / a_n: wave-local rows ----
    {
        const float asv = a_self[h * NC + lane];
        const float anv = a_neigh[h * NC + lane];
        for (int rr = 0; rr < 16; ++rr) {
            const int row = wave * 16 + rr;
            float f = fs[row][lane];
            float s1 = f * asv;
            float s2 = f * anv;
            #pragma unroll
            for (int off = 32; off > 0; off >>= 1) {
                s1 += __shfl_xor(s1, off);
                s2 += __shfl_xor(s2, off);
            }
            if (lane == 0) {
                asw[bh * NN + nb + row] = s1;
                anw[bh * NN + nb + row] = s2;
            }
        }
    }
    __syncthreads();   // fs complete for cross-wave reads

    // ---- emb half of out: relu(feats), FP32 float4 stores ----
    {
        const int row = tid >> 2, c0 = (tid & 3) * 16;
        float* ow = out + ((size_t)(b * NN) + nb + row) * 512 + h * NC + c0;
        #pragma unroll
        for (int e4 = 0; e4 < 4; ++e4) {
            float4 v;
            v.x = fmaxf(fs[row][c0 + e4 * 4 + 0], 0.f);
            v.y = fmaxf(fs[row][c0 + e4 * 4 + 1], 0.f);
            v.z = fmaxf(fs[row][c0 + e4 * 4 + 2], 0.f);
            v.w = fmaxf(fs[row][c0 + e4 * 4 + 3], 0.f);
            *(float4*)(ow + e4 * 4) = v;
        }
    }

    // ---- featw = feats^T bf16 [bh][c][n] ----
    {
        #pragma unroll
        for (int cc = 0; cc < 16; ++cc) {
            const int c = wave * 16 + cc;
            featw[((size_t)(bh * NC) + c) * NN + nb + lane] = f2bf(fs[lane][c]);
        }
    }
}

// ---------------------------------------------------------------------------
// K2 (rewritten): fused masked softmax + MFMA PV, K-split across 4 waves.
// Block = 256 thr handles 16 attention rows of one (b,h); wave w owns j-chunks
// w*4..w*4+3 (128 j's). V-frags loaded straight from featw into registers
// (L2-hot, no LDS staging). 2 barriers total. Cross-wave acc + denom
// reduction via LDS. Grid 1024 x 256. LDS ~19 KB. Output FP32.
// Layout conventions identical to the R4-passing kernel:
//   P A-frag: lane(m,q) holds P[m][q*8+j]; D: col=m, row=q*4+r.
// ---------------------------------------------------------------------------
__global__ __launch_bounds__(256) void k2_attn(
    const float* __restrict__ A, const uint16_t* __restrict__ featw,
    const float* __restrict__ asw, const float* __restrict__ anw,
    const float* __restrict__ biases, float* __restrict__ out)
{
    __shared__ float accbuf[4][16][65];   // 16.6 KB [wave][row][chan] (pad 65)
    __shared__ float sbuf[4][16];         // per-wave softmax-denom partials
    __shared__ __align__(16) float anl[NN];

    const int tid  = threadIdx.x;
    const int lane = tid & 63;
    const int wave = tid >> 6;
    const int blk  = blockIdx.x;
    const int it   = blk & 31;
    const int bh   = blk >> 5;
    const int h    = bh & 3;
    const int b    = bh >> 2;
    const int m    = lane & 15;
    const int q    = lane >> 4;
    const int i    = it * 16 + m;          // this lane's attention row

    anl[tid]       = anw[bh * NN + tid];
    anl[tid + 256] = anw[bh * NN + tid + 256];

    const float a_si = asw[bh * NN + i];
    const float* Ab  = A + (size_t)b * NN * NN + (size_t)i * NN;
    const uint16_t* fwb = featw + (size_t)(bh * NC) * NN;

    // ---- preload this wave's A slices (4 chunks x 32B/lane), no barriers
    //      between issue and use -> latency overlapped across 12+ waves/CU ----
    float4 a0[4], a1[4];
    #pragma unroll
    for (int cc = 0; cc < 4; ++cc) {
        const int ch = wave * 4 + cc;
        a0[cc] = *(const float4*)(Ab + ch * 32 + q * 8);
        a1[cc] = *(const float4*)(Ab + ch * 32 + q * 8 + 4);
    }
    // ---- preload V fragments (register-resident, 16 x 16B from L2) ----
    short8 vf[4][4];
    #pragma unroll
    for (int cc = 0; cc < 4; ++cc) {
        const int ch = wave * 4 + cc;
        #pragma unroll
        for (int ct = 0; ct < 4; ++ct)
            __builtin_memcpy(&vf[cc][ct],
                             fwb + ((size_t)(ct * 16 + m)) * NN + ch * 32 + q * 8, 16);
    }
    __syncthreads();   // anl ready

    f32x4 acc[4];
    #pragma unroll
    for (int ct = 0; ct < 4; ++ct) { acc[ct][0]=0.f; acc[ct][1]=0.f; acc[ct][2]=0.f; acc[ct][3]=0.f; }
    float ssum = 0.f;

    #pragma unroll
    for (int cc = 0; cc < 4; ++cc) {
        const int ch = wave * 4 + cc;
        float4 n0 = *(const float4*)&anl[ch * 32 + q * 8];
        float4 n1 = *(const float4*)&anl[ch * 32 + q * 8 + 4];
        float an[8] = {n0.x, n0.y, n0.z, n0.w, n1.x, n1.y, n1.z, n1.w};
        float aj[8] = {a0[cc].x, a0[cc].y, a0[cc].z, a0[cc].w,
                       a1[cc].x, a1[cc].y, a1[cc].z, a1[cc].w};
        float pv[8];
        #pragma unroll
        for (int k = 0; k < 8; ++k) {
            float e = a_si + an[k];
            float l = fmaxf(e, 0.2f * e);          // LeakyReLU(0.2)
            pv[k] = aj[k] * __expf(l);             // A in {0,1}: exact mask
            ssum += pv[k];
        }
        union { uint32_t u[4]; short8 s; } afu;
        afu.u[0] = (uint32_t)f2bf(pv[0]) | ((uint32_t)f2bf(pv[1]) << 16);
        afu.u[1] = (uint32_t)f2bf(pv[2]) | ((uint32_t)f2bf(pv[3]) << 16);
        afu.u[2] = (uint32_t)f2bf(pv[4]) | ((uint32_t)f2bf(pv[5]) << 16);
        afu.u[3] = (uint32_t)f2bf(pv[6]) | ((uint32_t)f2bf(pv[7]) << 16);
        short8 afrg = afu.s;

        #pragma unroll
        for (int ct = 0; ct < 4; ++ct)
            acc[ct] = __builtin_amdgcn_mfma_f32_16x16x32_bf16(afrg, vf[cc][ct], acc[ct], 0, 0, 0);
    }

    // ---- per-wave denom partial: reduce over q groups -> row m ----
    ssum += __shfl_xor(ssum, 16);
    ssum += __shfl_xor(ssum, 32);
    if (lane < 16) sbuf[wave][lane] = ssum;

    // ---- publish acc partials (write bank pattern: 2-way max, free) ----
    #pragma unroll
    for (int ct = 0; ct < 4; ++ct)
        #pragma unroll
        for (int r = 0; r < 4; ++r)
            accbuf[wave][q * 4 + r][ct * 16 + m] = acc[ct][r];
    __syncthreads();

    // ---- epilogue: 4 outputs/thread, contiguous 256B stores per row ----
    const int col = tid & 63;
    const int rg  = tid >> 6;
    const float bias_c = biases[h * NC + col];
    #pragma unroll
    for (int rr = 0; rr < 4; ++rr) {
        const int row = rg * 4 + rr;
        float s = sbuf[0][row] + sbuf[1][row] + sbuf[2][row] + sbuf[3][row];
        float v = accbuf[0][row][col] + accbuf[1][row][col] +
                  accbuf[2][row][col] + accbuf[3][row][col];
        float o = fmaxf(v / s + bias_c, 0.f);
        out[((size_t)(b * NN) + it * 16 + row) * 512 + 256 + h * NC + col] = o;
    }
}

// ---------------------------------------------------------------------------
extern "C" void kernel_launch(void* const* d_in, const int* in_sizes, int n_in,
                              void* d_out, int out_size, void* d_ws, size_t ws_size,
                              hipStream_t stream) {
    (void)in_sizes; (void)n_in; (void)out_size; (void)ws_size;
    const float* X       = (const float*)d_in[0];
    const float* A       = (const float*)d_in[1];
    const float* Kern    = (const float*)d_in[2];
    const float* biases  = (const float*)d_in[3];
    const float* a_self  = (const float*)d_in[4];
    const float* a_neigh = (const float*)d_in[5];
    float* out = (float*)d_out;

    uint16_t* featw = (uint16_t*)d_ws;                          // 2 MB bf16 feats^T
    float* asw = (float*)((char*)d_ws + 2097152);               // 64 KB
    float* anw = (float*)((char*)d_ws + 2097152 + 65536);       // 64 KB

    hipLaunchKernelGGL(k1_feats, dim3(256), dim3(256), 0, stream,
                       X, Kern, a_self, a_neigh, out, featw, asw, anw);
    hipLaunchKernelGGL(k2_attn, dim3(1024), dim3(256), 0, stream,
                       A, featw, asw, anw, biases, out);
}

// Round 6
// 89.393 us; speedup vs baseline: 1.0376x; 1.0376x over previous
//
#include <hip/hip_runtime.h>
#include <stdint.h>
#include <string.h>

// R6: decisive A/B/A probe. K2 byte-identical to R5. K1's serial per-wave
// shfl-chain reduction (16 rows x two 6-deep cross-lane chains) replaced by a
// parallel two-stage LDS reduction. If dur_us stays ~92.7, the timed window
// is pinned by harness 256 MiB re-poison fills running at the achievable HBM
// ceiling (6.3 TB/s) and kernel time is invisible -> roofline of the measured
// quantity. If K1 was the hidden pig, dur collapses.

#define NN 512
#define NF 128
#define NC 64

typedef __attribute__((ext_vector_type(8))) short short8;
typedef __attribute__((ext_vector_type(4))) float f32x4;

__device__ __forceinline__ uint16_t f2bf(float f) {
    union { float f; uint32_t u; } v; v.f = f;
    uint32_t u = v.u;
    u += 0x7FFF + ((u >> 16) & 1);   // RNE
    return (uint16_t)(u >> 16);
}

// ---------------------------------------------------------------------------
// K1: feats = X @ kernels[h] via bf16 MFMA (fp32 inputs converted on load).
// Writes: a_s/a_n (fp32 ws), featw = feats^T bf16 [bh][c][n] (ws),
// relu(feats) = emb half of out (FP32). Grid 256 x 256. LDS ~36 KB.
// a_s/a_n reduction: parallel two-stage (16 FMA/thread -> LDS -> 64-thread
// finalize) instead of R4/R5's 16-iteration serial shfl chains.
// ---------------------------------------------------------------------------
__global__ __launch_bounds__(256) void k1_feats(
    const float* __restrict__ X, const float* __restrict__ Kern,
    const float* __restrict__ a_self, const float* __restrict__ a_neigh,
    float* __restrict__ out, uint16_t* __restrict__ featw,
    float* __restrict__ asw, float* __restrict__ anw)
{
    __shared__ __align__(16) uint16_t Kt[64][136];  // kernels[h]^T bf16 [c][f]
    __shared__ float fs[64][65];                    // feats tile fp32 (pad 1)
    __shared__ float pas[4][64];                    // a_s partials [quarter][row]
    __shared__ float pan[4][64];                    // a_n partials

    const int tid  = threadIdx.x;
    const int lane = tid & 63;
    const int wave = tid >> 6;
    const int blk  = blockIdx.x;
    const int nt   = blk & 7;
    const int bh   = blk >> 3;
    const int h    = bh & 3;
    const int b    = bh >> 2;
    const int nb   = nt * 64;

    // ---- stage Kt[c][f] = bf16(kernels[h][f][c]) ----
    {
        const int f0 = tid >> 1, c0 = (tid & 1) * 32;
        const float* kp = Kern + h * (NF * NC) + f0 * NC + c0;
        #pragma unroll
        for (int s4 = 0; s4 < 8; ++s4) {
            float4 v = *(const float4*)(kp + s4 * 4);
            Kt[c0 + s4 * 4 + 0][f0] = f2bf(v.x);
            Kt[c0 + s4 * 4 + 1][f0] = f2bf(v.y);
            Kt[c0 + s4 * 4 + 2][f0] = f2bf(v.z);
            Kt[c0 + s4 * 4 + 3][f0] = f2bf(v.w);
        }
    }

    // ---- A fragments: X rows, fp32 -> bf16 in registers ----
    const int m = lane & 15;
    const int q = lane >> 4;
    short8 af[4];
    {
        const float* xr = X + ((size_t)(b * NN) + nb + wave * 16 + m) * NF + q * 8;
        #pragma unroll
        for (int kt = 0; kt < 4; ++kt) {
            float4 x0 = *(const float4*)(xr + kt * 32);
            float4 x1 = *(const float4*)(xr + kt * 32 + 4);
            union { uint32_t u[4]; short8 s; } r;
            r.u[0] = (uint32_t)f2bf(x0.x) | ((uint32_t)f2bf(x0.y) << 16);
            r.u[1] = (uint32_t)f2bf(x0.z) | ((uint32_t)f2bf(x0.w) << 16);
            r.u[2] = (uint32_t)f2bf(x1.x) | ((uint32_t)f2bf(x1.y) << 16);
            r.u[3] = (uint32_t)f2bf(x1.z) | ((uint32_t)f2bf(x1.w) << 16);
            af[kt] = r.s;
        }
    }
    __syncthreads();

    // ---- MFMA: wave computes feats[16 rows x 64 c] ----
    #pragma unroll
    for (int ct = 0; ct < 4; ++ct) {
        f32x4 acc = {0.f, 0.f, 0.f, 0.f};
        #pragma unroll
        for (int kt = 0; kt < 4; ++kt) {
            short8 bfr;
            __builtin_memcpy(&bfr, &Kt[ct * 16 + m][kt * 32 + q * 8], 16);
            acc = __builtin_amdgcn_mfma_f32_16x16x32_bf16(af[kt], bfr, acc, 0, 0, 0);
        }
        #pragma unroll
        for (int r = 0; r < 4; ++r)
            fs[wave * 16 + q * 4 + r][ct * 16 + m] = acc[r];   // C: col=m, row=q*4+r
    }
    __syncthreads();   // fs complete for cross-wave reads

    // ---- emb half of out: relu(feats), FP32 float4 stores ----
    {
        const int row = tid >> 2, c0 = (tid & 3) * 16;
        float* ow = out + ((size_t)(b * NN) + nb + row) * 512 + h * NC + c0;
        #pragma unroll
        for (int e4 = 0; e4 < 4; ++e4) {
            float4 v;
            v.x = fmaxf(fs[row][c0 + e4 * 4 + 0], 0.f);
            v.y = fmaxf(fs[row][c0 + e4 * 4 + 1], 0.f);
            v.z = fmaxf(fs[row][c0 + e4 * 4 + 2], 0.f);
            v.w = fmaxf(fs[row][c0 + e4 * 4 + 3], 0.f);
            *(float4*)(ow + e4 * 4) = v;
        }
    }

    // ---- featw = feats^T bf16 [bh][c][n] ----
    {
        #pragma unroll
        for (int cc = 0; cc < 16; ++cc) {
            const int c = wave * 16 + cc;
            featw[((size_t)(bh * NC) + c) * NN + nb + lane] = f2bf(fs[lane][c]);
        }
    }

    // ---- a_s/a_n partials: thread (row=lane, quarter=wave) does 16 FMAs ----
    {
        const int prow = lane;
        const int pq   = wave;
        const float* asp = a_self  + h * NC + pq * 16;
        const float* anp = a_neigh + h * NC + pq * 16;
        float ps = 0.f, pn = 0.f;
        #pragma unroll
        for (int k = 0; k < 16; ++k) {
            float f = fs[prow][pq * 16 + k];   // 2-way bank alias: free
            ps = fmaf(f, asp[k], ps);
            pn = fmaf(f, anp[k], pn);
        }
        pas[pq][prow] = ps;
        pan[pq][prow] = pn;
    }
    __syncthreads();

    // ---- finalize: 64 threads sum 4 partials, store ----
    if (tid < 64) {
        float s1 = pas[0][tid] + pas[1][tid] + pas[2][tid] + pas[3][tid];
        float s2 = pan[0][tid] + pan[1][tid] + pan[2][tid] + pan[3][tid];
        asw[bh * NN + nb + tid] = s1;
        anw[bh * NN + nb + tid] = s2;
    }
}

// ---------------------------------------------------------------------------
// K2 (byte-identical to R5): fused masked softmax + MFMA PV, K-split across
// 4 waves. Block = 256 thr handles 16 attention rows of one (b,h); wave w
// owns j-chunks w*4..w*4+3. V-frags register-resident from L2. 2 barriers.
// Grid 1024 x 256. LDS ~19 KB. Output FP32.
// ---------------------------------------------------------------------------
__global__ __launch_bounds__(256) void k2_attn(
    const float* __restrict__ A, const uint16_t* __restrict__ featw,
    const float* __restrict__ asw, const float* __restrict__ anw,
    const float* __restrict__ biases, float* __restrict__ out)
{
    __shared__ float accbuf[4][16][65];   // 16.6 KB [wave][row][chan]
    __shared__ float sbuf[4][16];         // per-wave softmax-denom partials
    __shared__ __align__(16) float anl[NN];

    const int tid  = threadIdx.x;
    const int lane = tid & 63;
    const int wave = tid >> 6;
    const int blk  = blockIdx.x;
    const int it   = blk & 31;
    const int bh   = blk >> 5;
    const int h    = bh & 3;
    const int b    = bh >> 2;
    const int m    = lane & 15;
    const int q    = lane >> 4;
    const int i    = it * 16 + m;          // this lane's attention row

    anl[tid]       = anw[bh * NN + tid];
    anl[tid + 256] = anw[bh * NN + tid + 256];

    const float a_si = asw[bh * NN + i];
    const float* Ab  = A + (size_t)b * NN * NN + (size_t)i * NN;
    const uint16_t* fwb = featw + (size_t)(bh * NC) * NN;

    float4 a0[4], a1[4];
    #pragma unroll
    for (int cc = 0; cc < 4; ++cc) {
        const int ch = wave * 4 + cc;
        a0[cc] = *(const float4*)(Ab + ch * 32 + q * 8);
        a1[cc] = *(const float4*)(Ab + ch * 32 + q * 8 + 4);
    }
    short8 vf[4][4];
    #pragma unroll
    for (int cc = 0; cc < 4; ++cc) {
        const int ch = wave * 4 + cc;
        #pragma unroll
        for (int ct = 0; ct < 4; ++ct)
            __builtin_memcpy(&vf[cc][ct],
                             fwb + ((size_t)(ct * 16 + m)) * NN + ch * 32 + q * 8, 16);
    }
    __syncthreads();   // anl ready

    f32x4 acc[4];
    #pragma unroll
    for (int ct = 0; ct < 4; ++ct) { acc[ct][0]=0.f; acc[ct][1]=0.f; acc[ct][2]=0.f; acc[ct][3]=0.f; }
    float ssum = 0.f;

    #pragma unroll
    for (int cc = 0; cc < 4; ++cc) {
        const int ch = wave * 4 + cc;
        float4 n0 = *(const float4*)&anl[ch * 32 + q * 8];
        float4 n1 = *(const float4*)&anl[ch * 32 + q * 8 + 4];
        float an[8] = {n0.x, n0.y, n0.z, n0.w, n1.x, n1.y, n1.z, n1.w};
        float aj[8] = {a0[cc].x, a0[cc].y, a0[cc].z, a0[cc].w,
                       a1[cc].x, a1[cc].y, a1[cc].z, a1[cc].w};
        float pv[8];
        #pragma unroll
        for (int k = 0; k < 8; ++k) {
            float e = a_si + an[k];
            float l = fmaxf(e, 0.2f * e);          // LeakyReLU(0.2)
            pv[k] = aj[k] * __expf(l);             // A in {0,1}: exact mask
            ssum += pv[k];
        }
        union { uint32_t u[4]; short8 s; } afu;
        afu.u[0] = (uint32_t)f2bf(pv[0]) | ((uint32_t)f2bf(pv[1]) << 16);
        afu.u[1] = (uint32_t)f2bf(pv[2]) | ((uint32_t)f2bf(pv[3]) << 16);
        afu.u[2] = (uint32_t)f2bf(pv[4]) | ((uint32_t)f2bf(pv[5]) << 16);
        afu.u[3] = (uint32_t)f2bf(pv[6]) | ((uint32_t)f2bf(pv[7]) << 16);
        short8 afrg = afu.s;

        #pragma unroll
        for (int ct = 0; ct < 4; ++ct)
            acc[ct] = __builtin_amdgcn_mfma_f32_16x16x32_bf16(afrg, vf[cc][ct], acc[ct], 0, 0, 0);
    }

    ssum += __shfl_xor(ssum, 16);
    ssum += __shfl_xor(ssum, 32);
    if (lane < 16) sbuf[wave][lane] = ssum;

    #pragma unroll
    for (int ct = 0; ct < 4; ++ct)
        #pragma unroll
        for (int r = 0; r < 4; ++r)
            accbuf[wave][q * 4 + r][ct * 16 + m] = acc[ct][r];
    __syncthreads();

    const int col = tid & 63;
    const int rg  = tid >> 6;
    const float bias_c = biases[h * NC + col];
    #pragma unroll
    for (int rr = 0; rr < 4; ++rr) {
        const int row = rg * 4 + rr;
        float s = sbuf[0][row] + sbuf[1][row] + sbuf[2][row] + sbuf[3][row];
        float v = accbuf[0][row][col] + accbuf[1][row][col] +
                  accbuf[2][row][col] + accbuf[3][row][col];
        float o = fmaxf(v / s + bias_c, 0.f);
        out[((size_t)(b * NN) + it * 16 + row) * 512 + 256 + h * NC + col] = o;
    }
}

// ---------------------------------------------------------------------------
extern "C" void kernel_launch(void* const* d_in, const int* in_sizes, int n_in,
                              void* d_out, int out_size, void* d_ws, size_t ws_size,
                              hipStream_t stream) {
    (void)in_sizes; (void)n_in; (void)out_size; (void)ws_size;
    const float* X       = (const float*)d_in[0];
    const float* A       = (const float*)d_in[1];
    const float* Kern    = (const float*)d_in[2];
    const float* biases  = (const float*)d_in[3];
    const float* a_self  = (const float*)d_in[4];
    const float* a_neigh = (const float*)d_in[5];
    float* out = (float*)d_out;

    uint16_t* featw = (uint16_t*)d_ws;                          // 2 MB bf16 feats^T
    float* asw = (float*)((char*)d_ws + 2097152);               // 64 KB
    float* anw = (float*)((char*)d_ws + 2097152 + 65536);       // 64 KB

    hipLaunchKernelGGL(k1_feats, dim3(256), dim3(256), 0, stream,
                       X, Kern, a_self, a_neigh, out, featw, asw, anw);
    hipLaunchKernelGGL(k2_attn, dim3(1024), dim3(256), 0, stream,
                       A, featw, asw, anw, biases, out);
}